// Round 3
// baseline (230.300 us; speedup 1.0000x reference)
//
#include <hip/hip_runtime.h>
#include <math.h>

#define SDIM 3
#define BDIM 32
#define NPRI 2000
#define LDIM 4
#define DDIM 78
#define NOFF 72
#define NSB (SDIM * BDIM)   // 96
#define CHUNK 128
#define NCHUNK 16           // ceil(2000/128)

// ws layout:
//   costws [2][96][4][2000] f  : 6,144,000 B
//   tgdiv  [32][36][8]      f  :    36,864 B   (gt offsets pre-divided by 799)
//   rowsws [2][96][4]       i  :     3,072 B
//   clsSum [2][2000]        f  :    16,000 B   (atomic acc, zeroed by prep)
//   regacc [2][8]           f  :        64 B   (atomic acc, zeroed by prep)

// ---------------------------------------------------------------------------
// prep: zero atomic accumulators, build tgdiv[b][jj][l*2+k] = gt[b][l][6+2jj+k]/799
__global__ __launch_bounds__(256) void prep_kernel(
    const float* __restrict__ gt, float* __restrict__ tgdiv,
    float* __restrict__ clsSum, float* __restrict__ regacc)
{
    int tid = blockIdx.x * 256 + threadIdx.x;
    if (tid < BDIM * 36 * 8) {
        int b = tid / 288, r = tid % 288, jj = r / 8, t = r % 8;
        int l = t >> 1, k = t & 1;
        tgdiv[tid] = gt[((size_t)b * LDIM + l) * DDIM + 6 + 2 * jj + k] / 799.0f;
    }
    if (tid < 2 * NPRI) clsSum[tid] = 0.0f;
    if (tid < 16) regacc[tid] = 0.0f;
}

// ---------------------------------------------------------------------------
// cost: grid (16, 96, 2), block 128 (2 waves). lane = prior, wave covers 64.
__global__ __launch_bounds__(128) void cost_kernel(
    const float* __restrict__ predsA, const float* __restrict__ predsB,
    const float* __restrict__ gt, const float* __restrict__ tgdiv,
    float* __restrict__ costws, float* __restrict__ clsSum)
{
    const int chunk = blockIdx.x;
    const int sb = blockIdx.y;
    const int branch = blockIdx.z;
    const float* preds = branch ? predsB : predsA;
    const int bimg = sb % BDIM;
    const int tid = threadIdx.x;
    const int base_n = chunk * CHUNK;
    const int ntile = min(CHUNK, NPRI - base_n);   // 128 or 80

    __shared__ float tile[CHUNK * DDIM];           // 39,936 B

    // coalesced float4 staging (base 16B aligned, count exact: ntile even)
    {
        const float4* src = (const float4*)(preds + ((size_t)sb * NPRI + base_n) * DDIM);
        float4* dst = (float4*)tile;
        const int nf4 = ntile * DDIM / 4;          // 2496 or 1560
        for (int k = tid; k < nf4; k += 128) dst[k] = src[k];
    }
    __syncthreads();

    const int i = tid;                             // prior within chunk
    if (i >= ntile) return;
    const int n = base_n + i;
    const float* p = &tile[i * DDIM];

    // block-uniform targets (geo raw, offsets pre-divided) -> scalar loads
    const float* gtb = gt + (size_t)bimg * LDIM * DDIM;
    const float* tgb = tgdiv + (size_t)bimg * 288;

    float offs0 = 0.f, offs1 = 0.f, offs2 = 0.f, offs3 = 0.f;
#pragma unroll 6
    for (int jj = 0; jj < 36; ++jj) {
        float pv0 = p[6 + 2 * jj];
        float pv1 = p[7 + 2 * jj];
        const float* t8 = tgb + jj * 8;
        offs0 += fabsf(pv0 - t8[0]); offs0 += fabsf(pv1 - t8[1]);
        offs1 += fabsf(pv0 - t8[2]); offs1 += fabsf(pv1 - t8[3]);
        offs2 += fabsf(pv0 - t8[4]); offs2 += fabsf(pv1 - t8[5]);
        offs3 += fabsf(pv0 - t8[6]); offs3 += fabsf(pv1 - t8[7]);
    }

    float a = p[0], b1 = p[1];
    float m = fmaxf(a, b1);
    float ea = expf(a - m), eb = expf(b1 - m);
    float score = eb / (ea + eb);

    float g0 = p[2], g1 = p[3], g2 = p[4], g3 = p[5];
    float offs[4] = {offs0, offs1, offs2, offs3};
    float* cw = costws + ((size_t)(branch * NSB + sb) * LDIM) * NPRI + n;
#pragma unroll
    for (int l = 0; l < LDIM; ++l) {
        float geo = fabsf(g0 - gtb[l * DDIM + 2]) + fabsf(g1 - gtb[l * DDIM + 3])
                  + fabsf(g2 - gtb[l * DDIM + 4]) + fabsf(g3 - gtb[l * DDIM + 5]);
        cw[(size_t)l * NPRI] = geo + offs[l] / 72.0f - score;
    }

    // all-negative focal term (matched correction applied in final_kernel)
    float lse = m + logf(ea + eb);
    float logpt = a - lse;
    float pt = expf(logpt);
    float om = 1.0f - pt;
    atomicAdd(&clsSum[branch * NPRI + n], -(0.1f * om * om * logpt));
}

// ---------------------------------------------------------------------------
// greedy: grid (96, 2), block 256. Shuffle-based argmin, jnp.argmin tie-break.
__global__ __launch_bounds__(256) void greedy_kernel(
    const float* __restrict__ costws, int* __restrict__ rowsws)
{
    const int sb = blockIdx.x, branch = blockIdx.y;
    const int tid = threadIdx.x;
    const int wv = tid >> 6, lane = tid & 63;

    __shared__ float cost[LDIM][NPRI];   // 32,000 B
    __shared__ float redv[4];
    __shared__ int   redi[4];

    const float4* src = (const float4*)(costws + (size_t)(branch * NSB + sb) * LDIM * NPRI);
    float4* dst = (float4*)&cost[0][0];
    for (int k = tid; k < LDIM * NPRI / 4; k += 256) dst[k] = src[k];
    __syncthreads();

    for (int l = 0; l < LDIM; ++l) {
        float bv = INFINITY; int bi = 0x7fffffff;
        for (int k = tid; k < NPRI; k += 256) {
            float v = cost[l][k];
            if (v < bv) { bv = v; bi = k; }      // ascending k: strict < = first occurrence
        }
#pragma unroll
        for (int off = 32; off > 0; off >>= 1) {
            float v2 = __shfl_down(bv, off);
            int   i2 = __shfl_down(bi, off);
            if (v2 < bv || (v2 == bv && i2 < bi)) { bv = v2; bi = i2; }
        }
        if (lane == 0) { redv[wv] = bv; redi[wv] = bi; }
        __syncthreads();
        if (tid == 0) {
            float fv = redv[0]; int fi = redi[0];
#pragma unroll
            for (int w = 1; w < 4; ++w) {
                if (redv[w] < fv || (redv[w] == fv && redi[w] < fi)) { fv = redv[w]; fi = redi[w]; }
            }
            rowsws[(branch * NSB + sb) * LDIM + l] = fi;
            cost[0][fi] = INFINITY; cost[1][fi] = INFINITY;
            cost[2][fi] = INFINITY; cost[3][fi] = INFINITY;
        }
        __syncthreads();
    }
}

// ---------------------------------------------------------------------------
// regiou: grid (96, 2), block 256 (wave per l). lane = offset index.
// regacc[branch*8 + l] += (rsum/4)/4 ; regacc[branch*8+4+l] += (1-iou)/4  (final /96)
__global__ __launch_bounds__(256) void regiou_kernel(
    const float* __restrict__ predsA, const float* __restrict__ predsB,
    const float* __restrict__ gt, const int* __restrict__ rowsws,
    float* __restrict__ regacc)
{
    const int sb = blockIdx.x, branch = blockIdx.y;
    const float* preds = branch ? predsB : predsA;
    const int tid = threadIdx.x;
    const int l = tid >> 6, lane = tid & 63;
    const int bimg = sb % BDIM;

    const int row = rowsws[(branch * NSB + sb) * LDIM + l];
    const float* pm = preds + ((size_t)sb * NPRI + row) * DDIM;
    const float* tg = gt + ((size_t)bimg * LDIM + l) * DDIM;

    float osum = 0.f, usum = 0.f, rterm = 0.f;

    // line-IoU terms: j = lane, and j = lane+64 for lane < 8
    {
        float rp = pm[6 + lane] * 799.0f;
        float rt = tg[6 + lane];
        bool inv = (rt < 0.0f) || (rt >= 800.0f);
        float ov = fminf(rp, rt) - fmaxf(rp, rt) + 30.0f;
        float un = fmaxf(rp, rt) - fminf(rp, rt) + 30.0f;
        if (!inv) { osum += ov; usum += un; }
    }
    if (lane < 8) {
        float rp = pm[6 + lane + 64] * 799.0f;
        float rt = tg[6 + lane + 64];
        bool inv = (rt < 0.0f) || (rt >= 800.0f);
        float ov = fminf(rp, rt) - fmaxf(rp, rt) + 30.0f;
        float un = fmaxf(rp, rt) - fminf(rp, rt) + 30.0f;
        if (!inv) { osum += ov; usum += un; }
    }
    // smooth-L1: lanes 0..3 handle the 4 dims
    if (lane < 4) {
        const float scv[4] = {71.0f, 799.0f, 180.0f, 71.0f};
        float s = scv[lane];
        float d = pm[2 + lane] * s - tg[2 + lane] * s;
        float ad = fabsf(d);
        rterm = (ad < 1.0f) ? 0.5f * d * d : ad - 0.5f;
    }

#pragma unroll
    for (int off = 32; off > 0; off >>= 1) {
        osum += __shfl_down(osum, off);
        usum += __shfl_down(usum, off);
        rterm += __shfl_down(rterm, off);
    }
    if (lane == 0) {
        float iou = osum / (usum + 1e-9f);
        atomicAdd(&regacc[branch * 8 + l], (rterm / 4.0f) / 4.0f);
        atomicAdd(&regacc[branch * 8 + 4 + l], (1.0f - iou) / 4.0f);
    }
}

// ---------------------------------------------------------------------------
// final: matched focal corrections, inst vectors, exact median (bitonic),
// weighted sum -> scalar. 1 block, 1024 threads.
__global__ __launch_bounds__(1024) void final_kernel(
    const float* __restrict__ predsA, const float* __restrict__ predsB,
    const float* __restrict__ clsSum, const float* __restrict__ regacc,
    const int* __restrict__ rowsws, const float* __restrict__ diff,
    float* __restrict__ out)
{
    __shared__ float corr[2][NPRI];
    __shared__ float instA[NPRI];
    __shared__ float instB[NPRI];
    __shared__ float sbuf[2048];
    __shared__ float red[1024];
    const int tid = threadIdx.x;

    for (int k = tid; k < 2 * NPRI; k += 1024) corr[0][k] = 0.0f;
    __syncthreads();

    if (tid < 2 * NSB * LDIM) {
        int branch = tid / (NSB * LDIM);
        int idx = tid % (NSB * LDIM);
        int sb = idx >> 2, l = idx & 3;
        int r = rowsws[(branch * NSB + sb) * LDIM + l];
        const float* p = (branch ? predsB : predsA) + ((size_t)sb * NPRI + r) * DDIM;
        float a = p[0], b1 = p[1];
        float m = fmaxf(a, b1);
        float ea = expf(a - m), eb = expf(b1 - m);
        float lse = m + logf(ea + eb);
        float lp0 = a - lse, lp1 = b1 - lse;
        float pt0 = expf(lp0), pt1 = expf(lp1);
        float om0 = 1.0f - pt0, om1 = 1.0f - pt1;
        float neg = -(0.1f * om0 * om0 * lp0);
        float pos = -(0.9f * om1 * om1 * lp1);
        atomicAdd(&corr[branch][r], pos - neg);
    }
    __syncthreads();

    const float cls_scale = 2.0f / 96.0f;
    for (int n = tid; n < NPRI; n += 1024) {
        float ia = (clsSum[n] + corr[0][n]) * cls_scale;
        float ib = (clsSum[NPRI + n] + corr[1][n]) * cls_scale;
#pragma unroll
        for (int l = 0; l < 4; ++l) {
            if (rowsws[(NSB - 1) * LDIM + l] == n)
                ia += (regacc[l] / 96.0f) * 0.5f + (regacc[4 + l] / 96.0f) * 2.0f;
            if (rowsws[(NSB + NSB - 1) * LDIM + l] == n)
                ib += (regacc[8 + l] / 96.0f) * 0.5f + (regacc[12 + l] / 96.0f) * 2.0f;
        }
        instA[n] = ia; instB[n] = ib;
        sbuf[n] = ia - ib;
    }
    if (tid < 2048 - NPRI) sbuf[NPRI + tid] = INFINITY;
    __syncthreads();

    for (int k = 2; k <= 2048; k <<= 1) {
        for (int j = k >> 1; j > 0; j >>= 1) {
            for (int i = tid; i < 2048; i += 1024) {
                int ixj = i ^ j;
                if (ixj > i) {
                    bool up = ((i & k) == 0);
                    float x = sbuf[i], y = sbuf[ixj];
                    if ((x > y) == up) { sbuf[i] = y; sbuf[ixj] = x; }
                }
            }
            __syncthreads();
        }
    }
    float delta = 0.5f * (sbuf[999] + sbuf[1000]);

    float acc = 0.0f;
    for (int n = tid; n < NPRI; n += 1024) {
        float dm = (diff[n] + diff[NPRI + n] + diff[2 * NPRI + n]) / 3.0f;
        acc += (1.0f - dm) * (instA[n] - 0.5f * delta)
             + dm * (instB[n] + 0.5f * delta);
    }
    red[tid] = acc;
    __syncthreads();
    for (int s = 512; s > 0; s >>= 1) {
        if (tid < s) red[tid] += red[tid + s];
        __syncthreads();
    }
    if (tid == 0) out[0] = red[0];
}

// ---------------------------------------------------------------------------
extern "C" void kernel_launch(void* const* d_in, const int* in_sizes, int n_in,
                              void* d_out, int out_size, void* d_ws, size_t ws_size,
                              hipStream_t stream)
{
    const float* predsA = (const float*)d_in[0];
    const float* predsB = (const float*)d_in[1];
    const float* gt     = (const float*)d_in[2];
    const float* diff   = (const float*)d_in[3];
    float* out = (float*)d_out;

    float* costws = (float*)d_ws;                         // 1,536,000 f
    float* tgdiv  = costws + 2 * NSB * LDIM * NPRI;       //     9,216 f
    int*   rowsws = (int*)(tgdiv + BDIM * 36 * 8);        //       768 i
    float* clsSum = (float*)(rowsws + 2 * NSB * LDIM);    //     4,000 f
    float* regacc = clsSum + 2 * NPRI;                    //        16 f

    prep_kernel<<<36, 256, 0, stream>>>(gt, tgdiv, clsSum, regacc);

    dim3 g1(NCHUNK, NSB, 2);
    cost_kernel<<<g1, 128, 0, stream>>>(predsA, predsB, gt, tgdiv, costws, clsSum);

    dim3 g2(NSB, 2);
    greedy_kernel<<<g2, 256, 0, stream>>>(costws, rowsws);

    regiou_kernel<<<g2, 256, 0, stream>>>(predsA, predsB, gt, rowsws, regacc);

    final_kernel<<<1, 1024, 0, stream>>>(predsA, predsB, clsSum, regacc,
                                         rowsws, diff, out);
}

// Round 4
// 202.245 us; speedup vs baseline: 1.1387x; 1.1387x over previous
//
#include <hip/hip_runtime.h>
#include <math.h>

#define SDIM 3
#define BDIM 32
#define NPRI 2000
#define LDIM 4
#define DDIM 78
#define NOFF 72
#define NSB (SDIM * BDIM)   // 96
#define CHUNK 128
#define NCHUNK 16

// ws layout:
//   costws [2][96][4][2000] f : 6,144,000 B
//   tgdiv  [32][36][8]      f :    36,864 B
//   rowsws [2][4]           i :        32 B  (last-sb rows only)
//   clsSum [2][2000]        f :    16,000 B  (atomic, zeroed in prep)
//   corrws [2][2000]        f :    16,000 B  (atomic, zeroed in prep)
//   regacc [2][8]           f :        64 B  (atomic, zeroed in prep)

// ---------------------------------------------------------------------------
__global__ __launch_bounds__(256) void prep_kernel(
    const float* __restrict__ gt, float* __restrict__ tgdiv,
    float* __restrict__ clsSum, float* __restrict__ corrws,
    float* __restrict__ regacc)
{
    int tid = blockIdx.x * 256 + threadIdx.x;
    if (tid < BDIM * 36 * 8) {
        int b = tid / 288, r = tid % 288, jj = r / 8, t = r % 8;
        int l = t >> 1, k = t & 1;
        tgdiv[tid] = gt[((size_t)b * LDIM + l) * DDIM + 6 + 2 * jj + k] / 799.0f;
    }
    if (tid < 2 * NPRI) { clsSum[tid] = 0.0f; corrws[tid] = 0.0f; }
    if (tid < 16) regacc[tid] = 0.0f;
}

// ---------------------------------------------------------------------------
// cost: grid (16, 96, 2), block 256 (4 waves). 2 threads/prior, even/odd lane
// halves combined via shfl_xor. LDS = tile only (39,936 B) -> 4 blocks/CU.
__global__ __launch_bounds__(256) void cost_kernel(
    const float* __restrict__ predsA, const float* __restrict__ predsB,
    const float* __restrict__ gt, const float* __restrict__ tgdiv,
    float* __restrict__ costws, float* __restrict__ clsSum)
{
    const int chunk = blockIdx.x;
    const int sb = blockIdx.y;
    const int branch = blockIdx.z;
    const float* preds = branch ? predsB : predsA;
    const int bimg = sb % BDIM;
    const int tid = threadIdx.x;
    const int base_n = chunk * CHUNK;
    const int ntile = min(CHUNK, NPRI - base_n);   // 128 or 80

    __shared__ float tile[CHUNK * DDIM];           // 39,936 B exactly

    {
        const float4* src = (const float4*)(preds + ((size_t)sb * NPRI + base_n) * DDIM);
        float4* dst = (float4*)tile;
        const int nf4 = ntile * DDIM / 4;          // 2496 or 1560
        for (int k = tid; k < nf4; k += 256) dst[k] = src[k];
    }
    __syncthreads();

    const int wv = tid >> 6, lane = tid & 63;
    const int i = wv * 32 + (lane >> 1);           // prior within chunk
    const int h = lane & 1;                        // offset half (0: j<36, 1: j>=36)
    if (i >= ntile) return;
    const int n = base_n + i;
    const float* p = &tile[i * DDIM];

    const float* gtb = gt + (size_t)bimg * LDIM * DDIM;   // uniform -> s_load
    const float* tgb = tgdiv + (size_t)bimg * 288;        // uniform -> s_load

    float offs0 = 0.f, offs1 = 0.f, offs2 = 0.f, offs3 = 0.f;
    const int jj0 = h * 18;
#pragma unroll 6
    for (int jj = jj0; jj < jj0 + 18; ++jj) {
        float pv0 = p[6 + 2 * jj];
        float pv1 = p[7 + 2 * jj];
        const float* t8 = tgb + jj * 8;
        offs0 += fabsf(pv0 - t8[0]); offs0 += fabsf(pv1 - t8[1]);
        offs1 += fabsf(pv0 - t8[2]); offs1 += fabsf(pv1 - t8[3]);
        offs2 += fabsf(pv0 - t8[4]); offs2 += fabsf(pv1 - t8[5]);
        offs3 += fabsf(pv0 - t8[6]); offs3 += fabsf(pv1 - t8[7]);
    }
    // combine halves (partner lane differs only in h)
    offs0 += __shfl_xor(offs0, 1);
    offs1 += __shfl_xor(offs1, 1);
    offs2 += __shfl_xor(offs2, 1);
    offs3 += __shfl_xor(offs3, 1);

    if (h == 0) {
        float a = p[0], b1 = p[1];
        float m = fmaxf(a, b1);
        float ea = expf(a - m), eb = expf(b1 - m);
        float score = eb / (ea + eb);
        float g0 = p[2], g1 = p[3], g2 = p[4], g3 = p[5];
        float offs[4] = {offs0, offs1, offs2, offs3};
        float* cw = costws + ((size_t)(branch * NSB + sb) * LDIM) * NPRI + n;
#pragma unroll
        for (int l = 0; l < LDIM; ++l) {
            float geo = fabsf(g0 - gtb[l * DDIM + 2]) + fabsf(g1 - gtb[l * DDIM + 3])
                      + fabsf(g2 - gtb[l * DDIM + 4]) + fabsf(g3 - gtb[l * DDIM + 5]);
            cw[(size_t)l * NPRI] = geo + offs[l] / 72.0f - score;
        }
        float lse = m + logf(ea + eb);
        float logpt = a - lse;
        float pt = expf(logpt);
        float om = 1.0f - pt;
        atomicAdd(&clsSum[branch * NPRI + n], -(0.1f * om * om * logpt));
    }
}

// ---------------------------------------------------------------------------
// fused greedy + regiou + matched focal corrections. grid (96, 2), block 256.
__global__ __launch_bounds__(256) void assignloss_kernel(
    const float* __restrict__ predsA, const float* __restrict__ predsB,
    const float* __restrict__ gt, const float* __restrict__ costws,
    int* __restrict__ rowsws, float* __restrict__ regacc,
    float* __restrict__ corrws)
{
    const int sb = blockIdx.x, branch = blockIdx.y;
    const float* preds = branch ? predsB : predsA;
    const int tid = threadIdx.x;
    const int wv = tid >> 6, lane = tid & 63;
    const int bimg = sb % BDIM;

    __shared__ float cost[LDIM][NPRI];   // 32,000 B
    __shared__ float redv[4];
    __shared__ int   redi[4];
    __shared__ int   rows_lds[LDIM];

    const float4* src = (const float4*)(costws + (size_t)(branch * NSB + sb) * LDIM * NPRI);
    float4* dst = (float4*)&cost[0][0];
    for (int k = tid; k < LDIM * NPRI / 4; k += 256) dst[k] = src[k];
    __syncthreads();

    // ---- greedy argmin (jnp.argmin tie-break: lowest index wins) ----
    for (int l = 0; l < LDIM; ++l) {
        float bv = INFINITY; int bi = 0x7fffffff;
        for (int k = tid; k < NPRI; k += 256) {
            float v = cost[l][k];
            if (v < bv) { bv = v; bi = k; }
        }
#pragma unroll
        for (int off = 32; off > 0; off >>= 1) {
            float v2 = __shfl_down(bv, off);
            int   i2 = __shfl_down(bi, off);
            if (v2 < bv || (v2 == bv && i2 < bi)) { bv = v2; bi = i2; }
        }
        if (lane == 0) { redv[wv] = bv; redi[wv] = bi; }
        __syncthreads();
        if (tid == 0) {
            float fv = redv[0]; int fi = redi[0];
#pragma unroll
            for (int w = 1; w < 4; ++w)
                if (redv[w] < fv || (redv[w] == fv && redi[w] < fi)) { fv = redv[w]; fi = redi[w]; }
            rows_lds[l] = fi;
            cost[0][fi] = INFINITY; cost[1][fi] = INFINITY;
            cost[2][fi] = INFINITY; cost[3][fi] = INFINITY;
        }
        __syncthreads();
    }
    if (tid < LDIM && sb == NSB - 1) rowsws[branch * LDIM + tid] = rows_lds[tid];

    // ---- regiou + matched focal corr: wave wv handles target l = wv ----
    const int l = wv;
    const int row = rows_lds[l];
    const float* pm = preds + ((size_t)sb * NPRI + row) * DDIM;   // coalesced per wave
    const float* tg = gt + ((size_t)bimg * LDIM + l) * DDIM;

    float osum = 0.f, usum = 0.f, rterm = 0.f;
    {
        float rp = pm[6 + lane] * 799.0f;
        float rt = tg[6 + lane];
        bool inv = (rt < 0.0f) || (rt >= 800.0f);
        float ov = fminf(rp, rt) - fmaxf(rp, rt) + 30.0f;
        float un = fmaxf(rp, rt) - fminf(rp, rt) + 30.0f;
        if (!inv) { osum += ov; usum += un; }
    }
    if (lane < 8) {
        float rp = pm[6 + lane + 64] * 799.0f;
        float rt = tg[6 + lane + 64];
        bool inv = (rt < 0.0f) || (rt >= 800.0f);
        float ov = fminf(rp, rt) - fmaxf(rp, rt) + 30.0f;
        float un = fmaxf(rp, rt) - fminf(rp, rt) + 30.0f;
        if (!inv) { osum += ov; usum += un; }
    }
    if (lane < 4) {
        const float scv[4] = {71.0f, 799.0f, 180.0f, 71.0f};
        float s = scv[lane];
        float d = pm[2 + lane] * s - tg[2 + lane] * s;
        float ad = fabsf(d);
        rterm = (ad < 1.0f) ? 0.5f * d * d : ad - 0.5f;
    }
#pragma unroll
    for (int off = 32; off > 0; off >>= 1) {
        osum += __shfl_down(osum, off);
        usum += __shfl_down(usum, off);
        rterm += __shfl_down(rterm, off);
    }
    if (lane == 0) {
        float iou = osum / (usum + 1e-9f);
        atomicAdd(&regacc[branch * 8 + l], (rterm / 4.0f) / 4.0f);
        atomicAdd(&regacc[branch * 8 + 4 + l], (1.0f - iou) / 4.0f);

        // matched focal correction (pos term replaces neg term for this prior)
        float a = pm[0], b1 = pm[1];
        float m = fmaxf(a, b1);
        float ea = expf(a - m), eb = expf(b1 - m);
        float lse = m + logf(ea + eb);
        float lp0 = a - lse, lp1 = b1 - lse;
        float pt0 = expf(lp0), pt1 = expf(lp1);
        float om0 = 1.0f - pt0, om1 = 1.0f - pt1;
        float neg = -(0.1f * om0 * om0 * lp0);
        float pos = -(0.9f * om1 * om1 * lp1);
        atomicAdd(&corrws[branch * NPRI + row], pos - neg);
    }
}

// ---------------------------------------------------------------------------
// final: inst vectors, exact median (bitonic 2048), weighted sum -> scalar.
__global__ __launch_bounds__(1024) void final_kernel(
    const float* __restrict__ clsSum, const float* __restrict__ corrws,
    const float* __restrict__ regacc, const int* __restrict__ rowsws,
    const float* __restrict__ diff, float* __restrict__ out)
{
    __shared__ float instA[NPRI];
    __shared__ float instB[NPRI];
    __shared__ float sbuf[2048];
    __shared__ float red[1024];
    const int tid = threadIdx.x;

    for (int n = tid; n < NPRI; n += 1024) {
        float ia = (clsSum[n] + corrws[n]) * (2.0f / 96.0f);
        float ib = (clsSum[NPRI + n] + corrws[NPRI + n]) * (2.0f / 96.0f);
#pragma unroll
        for (int l = 0; l < 4; ++l) {
            if (rowsws[l] == n)
                ia += (regacc[l] / 96.0f) * 0.5f + (regacc[4 + l] / 96.0f) * 2.0f;
            if (rowsws[4 + l] == n)
                ib += (regacc[8 + l] / 96.0f) * 0.5f + (regacc[12 + l] / 96.0f) * 2.0f;
        }
        instA[n] = ia; instB[n] = ib;
        sbuf[n] = ia - ib;
    }
    if (tid < 2048 - NPRI) sbuf[NPRI + tid] = INFINITY;
    __syncthreads();

    for (int k = 2; k <= 2048; k <<= 1) {
        for (int j = k >> 1; j > 0; j >>= 1) {
            for (int i = tid; i < 2048; i += 1024) {
                int ixj = i ^ j;
                if (ixj > i) {
                    bool up = ((i & k) == 0);
                    float x = sbuf[i], y = sbuf[ixj];
                    if ((x > y) == up) { sbuf[i] = y; sbuf[ixj] = x; }
                }
            }
            __syncthreads();
        }
    }
    float delta = 0.5f * (sbuf[999] + sbuf[1000]);

    float acc = 0.0f;
    for (int n = tid; n < NPRI; n += 1024) {
        float dm = (diff[n] + diff[NPRI + n] + diff[2 * NPRI + n]) / 3.0f;
        acc += (1.0f - dm) * (instA[n] - 0.5f * delta)
             + dm * (instB[n] + 0.5f * delta);
    }
    red[tid] = acc;
    __syncthreads();
    for (int s = 512; s > 0; s >>= 1) {
        if (tid < s) red[tid] += red[tid + s];
        __syncthreads();
    }
    if (tid == 0) out[0] = red[0];
}

// ---------------------------------------------------------------------------
extern "C" void kernel_launch(void* const* d_in, const int* in_sizes, int n_in,
                              void* d_out, int out_size, void* d_ws, size_t ws_size,
                              hipStream_t stream)
{
    const float* predsA = (const float*)d_in[0];
    const float* predsB = (const float*)d_in[1];
    const float* gt     = (const float*)d_in[2];
    const float* diff   = (const float*)d_in[3];
    float* out = (float*)d_out;

    float* costws = (float*)d_ws;                         // 1,536,000 f
    float* tgdiv  = costws + 2 * NSB * LDIM * NPRI;       //     9,216 f
    int*   rowsws = (int*)(tgdiv + BDIM * 36 * 8);        //         8 i
    float* clsSum = (float*)(rowsws + 8);                 //     4,000 f
    float* corrws = clsSum + 2 * NPRI;                    //     4,000 f
    float* regacc = corrws + 2 * NPRI;                    //        16 f

    prep_kernel<<<40, 256, 0, stream>>>(gt, tgdiv, clsSum, corrws, regacc);

    dim3 g1(NCHUNK, NSB, 2);
    cost_kernel<<<g1, 256, 0, stream>>>(predsA, predsB, gt, tgdiv, costws, clsSum);

    dim3 g2(NSB, 2);
    assignloss_kernel<<<g2, 256, 0, stream>>>(predsA, predsB, gt, costws,
                                              rowsws, regacc, corrws);

    final_kernel<<<1, 1024, 0, stream>>>(clsSum, corrws, regacc, rowsws, diff, out);
}